// Round 10
// baseline (352.755 us; speedup 1.0000x reference)
//
#include <hip/hip_runtime.h>
#include <math.h>

#define N_NODES 50000
#define D_MODEL 128
#define N_HEADS 8
#define HEAD_C 16
#define E_DIM 16
#define N_EDGES 800000

typedef __attribute__((ext_vector_type(8))) short bf16x8;
typedef __attribute__((ext_vector_type(4))) float f32x4;

__device__ inline ushort f2bf(float f) {
    unsigned u = __float_as_uint(f);
    unsigned r = (u + 0x7fffu + ((u >> 16) & 1u)) >> 16;
    return (ushort)r;
}
__device__ inline float bf2f(ushort h) { return __uint_as_float(((unsigned)h) << 16); }
__device__ inline uint pack2(float a, float b) {
    return (uint)f2bf(a) | ((uint)f2bf(b) << 16);
}

// ---------------- Weight prep: transpose + bf16 cast (natural column order) ----
__global__ void prep_weights(const float* __restrict__ wq, const float* __restrict__ wk,
                             const float* __restrict__ wv, const float* __restrict__ wsk,
                             const float* __restrict__ bq, const float* __restrict__ bk,
                             const float* __restrict__ bv, const float* __restrict__ bsk,
                             const float* __restrict__ w1, const float* __restrict__ w2,
                             ushort* __restrict__ wqkvsT, float* __restrict__ bqkvs,
                             ushort* __restrict__ w1T, ushort* __restrict__ w2T)
{
    int idx = blockIdx.x * 256 + threadIdx.x;          // 0..65535
    {   // wqkvsT [512][128] <- {wq|wk|wv|wsk}[128][128] transposed
        int m = idx >> 7, kk = idx & 127;
        int b = m >> 7, ch = m & 127;
        const float* src = (b == 0) ? wq : (b == 1) ? wk : (b == 2) ? wv : wsk;
        wqkvsT[idx] = f2bf(src[kk * 128 + ch]);
    }
    if (idx < 256 * 128) {   // w1T [256][128] <- w1[128][256]
        int m = idx >> 7, k = idx & 127;
        w1T[idx] = f2bf(w1[k * 256 + m]);
    }
    if (idx < 128 * 256) {   // w2T [128][256] <- w2[256][128]
        int m = idx >> 8, k = idx & 255;
        w2T[idx] = f2bf(w2[k * 128 + m]);
    }
    if (idx < 512) {
        int b = idx >> 7, ch = idx & 127;
        const float* bb = (b == 0) ? bq : (b == 1) ? bk : (b == 2) ? bv : bsk;
        bqkvs[idx] = bb[ch];
    }
}

// ---------------- LayerNorm (LN1): one wave per row, bf16 out ----------------
__global__ void ln_kernel(const float* __restrict__ in, const float* __restrict__ g,
                          const float* __restrict__ b, ushort* __restrict__ out, int n)
{
    int node = blockIdx.x * 4 + (threadIdx.x >> 6);
    int lane = threadIdx.x & 63;
    if (node >= n) return;
    size_t base = (size_t)node * D_MODEL;
    float v0 = in[base + lane];
    float v1 = in[base + lane + 64];
    float s  = v0 + v1;
    float ss = v0 * v0 + v1 * v1;
    #pragma unroll
    for (int off = 32; off > 0; off >>= 1) {
        s  += __shfl_xor(s,  off, 64);
        ss += __shfl_xor(ss, off, 64);
    }
    float mu  = s * (1.0f / 128.0f);
    float var = ss * (1.0f / 128.0f) - mu * mu;
    float rs  = rsqrtf(var + 1e-5f);
    out[base + lane]      = f2bf((v0 - mu) * rs * g[lane]      + b[lane]);
    out[base + lane + 64] = f2bf((v1 - mu) * rs * g[lane + 64] + b[lane + 64]);
}

// ---------------- bf16 MFMA GEMM, BM=128 x BN=64 (round-5 proven config) ----------
__global__ __launch_bounds__(256) void mfma_gemm(
    const ushort* __restrict__ A, const ushort* __restrict__ WT,
    const float* __restrict__ bias, const float* __restrict__ addsrc,
    void* __restrict__ Y, int nrows, int K, int M, int act, int outf32)
{
    __shared__ __align__(16) ushort Al[128 * 128];   // 32 KB
    __shared__ __align__(16) ushort Wl[64 * 128];    // 16 KB
    int tid = threadIdx.x;
    int wv = tid >> 6, lane = tid & 63;
    int row0 = blockIdx.x * 128;
    int col0 = blockIdx.y * 64;

    f32x4 acc[2][4];
    #pragma unroll
    for (int i = 0; i < 2; ++i)
        #pragma unroll
        for (int j = 0; j < 4; ++j) acc[i][j] = (f32x4){0.f, 0.f, 0.f, 0.f};

    for (int kc = 0; kc < K; kc += 128) {
        __syncthreads();
        #pragma unroll
        for (int i = 0; i < 8; ++i) {
            int c = tid + i * 256;
            int r = c >> 4, c16 = c & 15;
            int gr = row0 + r;
            ulonglong2 val = {0ull, 0ull};
            if (gr < nrows) val = *(const ulonglong2*)(A + (size_t)gr * K + kc + c16 * 8);
            int byte = r * 256 + ((c16 * 16) ^ ((r & 7) << 4));
            *(ulonglong2*)((char*)Al + byte) = val;
        }
        #pragma unroll
        for (int i = 0; i < 4; ++i) {
            int c = tid + i * 256;
            int r = c >> 4, c16 = c & 15;
            ulonglong2 val = *(const ulonglong2*)(WT + (size_t)(col0 + r) * K + kc + c16 * 8);
            int byte = r * 256 + ((c16 * 16) ^ ((r & 7) << 4));
            *(ulonglong2*)((char*)Wl + byte) = val;
        }
        __syncthreads();
        #pragma unroll
        for (int ks = 0; ks < 4; ++ks) {
            bf16x8 af[2], bfr[4];
            #pragma unroll
            for (int rt = 0; rt < 2; ++rt) {
                int r = wv * 32 + rt * 16 + (lane & 15);
                int byte = r * 256 + ((ks * 64 + (lane >> 4) * 16) ^ ((r & 7) << 4));
                af[rt] = *(const bf16x8*)((const char*)Al + byte);
            }
            #pragma unroll
            for (int ct = 0; ct < 4; ++ct) {
                int r = ct * 16 + (lane & 15);
                int byte = r * 256 + ((ks * 64 + (lane >> 4) * 16) ^ ((r & 7) << 4));
                bfr[ct] = *(const bf16x8*)((const char*)Wl + byte);
            }
            #pragma unroll
            for (int rt = 0; rt < 2; ++rt)
                #pragma unroll
                for (int ct = 0; ct < 4; ++ct)
                    acc[rt][ct] = __builtin_amdgcn_mfma_f32_16x16x32_bf16(
                        af[rt], bfr[ct], acc[rt][ct], 0, 0, 0);
        }
    }
    #pragma unroll
    for (int rt = 0; rt < 2; ++rt) {
        #pragma unroll
        for (int ct = 0; ct < 4; ++ct) {
            int gcol = col0 + ct * 16 + (lane & 15);
            float bv = bias[gcol];
            #pragma unroll
            for (int r = 0; r < 4; ++r) {
                int grow = row0 + wv * 32 + rt * 16 + (lane >> 4) * 4 + r;
                if (grow >= nrows) continue;
                float val = acc[rt][ct][r] + bv;
                if (act == 1)
                    val = 0.5f * val * (1.0f + erff(val * 0.70710678118654752f));
                size_t idx = (size_t)grow * M + gcol;
                if (outf32) {
                    float* Yf = (float*)Y;
                    if (addsrc) val += addsrc[idx];
                    Yf[idx] = val;
                } else {
                    ((ushort*)Y)[idx] = f2bf(val);
                }
            }
        }
    }
}

// ---------------- Counting sort of edges by destination ----------------
__global__ void hist_kernel(const int* __restrict__ dst, int* __restrict__ deg)
{
    int e = blockIdx.x * 256 + threadIdx.x;
    if (e < N_EDGES) atomicAdd(&deg[dst[e]], 1);
}

__global__ void scan1_kernel(const int* __restrict__ deg, int* __restrict__ off,
                             int* __restrict__ bsum)
{
    __shared__ int sm[256];
    int i = blockIdx.x * 256 + threadIdx.x;
    int v = (i < N_NODES) ? deg[i] : 0;
    sm[threadIdx.x] = v;
    __syncthreads();
    #pragma unroll
    for (int d = 1; d < 256; d <<= 1) {
        int t = (threadIdx.x >= d) ? sm[threadIdx.x - d] : 0;
        __syncthreads();
        sm[threadIdx.x] += t;
        __syncthreads();
    }
    if (i < N_NODES) off[i] = sm[threadIdx.x] - v;
    if (threadIdx.x == 255) bsum[blockIdx.x] = sm[255];
}

__global__ void scan2_kernel(int* __restrict__ bsum, int nb)
{
    __shared__ int sm[256];
    int v = (threadIdx.x < nb) ? bsum[threadIdx.x] : 0;
    sm[threadIdx.x] = v;
    __syncthreads();
    #pragma unroll
    for (int d = 1; d < 256; d <<= 1) {
        int t = (threadIdx.x >= d) ? sm[threadIdx.x - d] : 0;
        __syncthreads();
        sm[threadIdx.x] += t;
        __syncthreads();
    }
    if (threadIdx.x < nb) bsum[threadIdx.x] = sm[threadIdx.x] - v;
}

__global__ void scan3_kernel(int* __restrict__ off, const int* __restrict__ bsum,
                             int* __restrict__ cursor)
{
    int i = blockIdx.x * 256 + threadIdx.x;
    if (i < N_NODES) {
        int o = off[i] + bsum[blockIdx.x];
        off[i] = o;
        cursor[i] = o;
    }
}

// scatter: src id + bf16 edge_attr row in destination-sorted order
// (random writes here buy SEQUENTIAL hot-loop reads in node_attn — r6 lesson)
__global__ void scatter_kernel(const int* __restrict__ dst, const int* __restrict__ src,
                               const float* __restrict__ eattr, int* __restrict__ cursor,
                               int* __restrict__ src_s, ushort* __restrict__ eattr_s)
{
    int e = blockIdx.x * 256 + threadIdx.x;
    if (e < N_EDGES) {
        int p = atomicAdd(&cursor[dst[e]], 1);
        src_s[p] = src[e];
        const float4* s4 = (const float4*)(eattr + (size_t)e * E_DIM);
        float4 f0 = s4[0], f1 = s4[1], f2 = s4[2], f3 = s4[3];
        uint4 u0, u1;
        u0.x = pack2(f0.x, f0.y); u0.y = pack2(f0.z, f0.w);
        u0.z = pack2(f1.x, f1.y); u0.w = pack2(f1.z, f1.w);
        u1.x = pack2(f2.x, f2.y); u1.y = pack2(f2.z, f2.w);
        u1.z = pack2(f3.x, f3.y); u1.w = pack2(f3.z, f3.w);
        uint4* d4 = (uint4*)(eattr_s + (size_t)p * E_DIM);
        d4[0] = u0; d4[1] = u1;
    }
}

// ---------------- Fused node attention: 2 waves/node + beta + residual + LN2 -------
// 512-thread block = 8 waves = 4 nodes x 2 half-waves. Each half-wave runs the
// r7 dual-state loop on HALF the node's edge list (state is a plain sum since
// there's no running max -> mergeable); partials merge via LDS, half-0 wave does
// the epilogue. Lane l owns head h=l>>3, channels 2l,2l+1.
#define ATTN_STEP(P, S, A0, A1, E0, E1) do {                                         \
    int sv_ = src_s[P];                                                              \
    uint eap_ = *(const uint*)(eattr_s + (size_t)(P) * E_DIM + j2);                  \
    float ea0_ = bf2f((ushort)eap_), ea1_ = bf2f((ushort)(eap_ >> 16));              \
    size_t sb_ = (size_t)sv_ * 512;                                                  \
    uint kp_ = *(const uint*)(qkvs + sb_ + 128 + 2 * lane);                          \
    uint vp_ = *(const uint*)(qkvs + sb_ + 256 + 2 * lane);                          \
    float p_ = q0 * bf2f((ushort)kp_) + q1 * bf2f((ushort)(kp_ >> 16))               \
             + ea0_ * qp0 + ea1_ * qp1;                                              \
    p_ += __shfl_xor(p_, 1, 64);                                                     \
    p_ += __shfl_xor(p_, 2, 64);                                                     \
    p_ += __shfl_xor(p_, 4, 64);                                                     \
    float w_ = __expf(fminf(p_, 60.f));                                              \
    S  += w_;                                                                        \
    A0 += w_ * bf2f((ushort)vp_);                                                    \
    A1 += w_ * bf2f((ushort)(vp_ >> 16));                                            \
    E0 += w_ * ea0_;                                                                 \
    E1 += w_ * ea1_;                                                                 \
} while (0)

__global__ __launch_bounds__(512) void node_attn(
                          const ushort* __restrict__ qkvs, const float* __restrict__ x,
                          const float* __restrict__ we, const float* __restrict__ wbeta,
                          const float* __restrict__ ln2g, const float* __restrict__ ln2b,
                          const int* __restrict__ off, const int* __restrict__ deg,
                          const int* __restrict__ src_s, const ushort* __restrict__ eattr_s,
                          float* __restrict__ xnew, ushort* __restrict__ h2)
{
    __shared__ float wl[E_DIM * 128];     // we row-major [16][128], 8 KB
    __shared__ float weT[128 * 17];       // we transposed [128][16+pad], 8.5 KB
    __shared__ float sc4[8][128];         // per-wave scratch, 4 KB
    __shared__ float part[8][5][64];      // per-wave partials (S,A0,A1,E0,E1), 10 KB
    for (int t = threadIdx.x; t < E_DIM * 32; t += 512)
        *(float4*)&wl[t * 4] = *(const float4*)&we[t * 4];
    for (int t = threadIdx.x; t < E_DIM * 128; t += 512) {
        int j = t >> 7, ch = t & 127;
        weT[ch * 17 + j] = we[t];
    }
    __syncthreads();

    int wvid = threadIdx.x >> 6;          // 0..7
    int node = blockIdx.x * 4 + (wvid >> 1);
    int half = wvid & 1;
    int lane = threadIdx.x & 63;

    int j2 = (lane & 7) * 2;              // this lane's ea component pair
    int hb = (lane >> 3) * 16;            // head channel base

    size_t nb = (size_t)node * 512;
    uint qp = *(const uint*)(qkvs + nb + 2 * lane);
    float q0r = bf2f((ushort)qp), q1r = bf2f((ushort)(qp >> 16));

    // qproj[h, j] = sum_c we[j, h*16+c] * q[h*16+c]  (computed by both halves)
    sc4[wvid][2 * lane]     = q0r;
    sc4[wvid][2 * lane + 1] = q1r;
    float qp0 = 0.f, qp1 = 0.f;
    #pragma unroll
    for (int c = 0; c < 16; ++c) {
        float qc = sc4[wvid][hb + c];
        qp0 += qc * weT[(hb + c) * 17 + j2];
        qp1 += qc * weT[(hb + c) * 17 + j2 + 1];
    }
    float q0 = q0r * 0.25f, q1 = q1r * 0.25f;   // fold 1/sqrt(C)
    qp0 *= 0.25f; qp1 *= 0.25f;

    float SA = 0.f, A0a = 0.f, A1a = 0.f, E0a = 0.f, E1a = 0.f;
    float SB = 0.f, A0b = 0.f, A1b = 0.f, E0b = 0.f, E1b = 0.f;

    int o = off[node], dg = deg[node];
    int dg2 = (dg + 1) >> 1;
    int st  = o + half * dg2;
    int cnt = half ? (dg - dg2) : dg2;

    int i = 0;
    for (; i + 2 <= cnt; i += 2) {
        ATTN_STEP(st + i,     SA, A0a, A1a, E0a, E1a);
        ATTN_STEP(st + i + 1, SB, A0b, A1b, E0b, E1b);
    }
    if (i < cnt)
        ATTN_STEP(st + i, SA, A0a, A1a, E0a, E1a);

    float S  = SA + SB;
    float A0 = A0a + A0b, A1 = A1a + A1b;
    float E0 = E0a + E0b, E1 = E1a + E1b;

    // merge the two half-wave partials through LDS
    part[wvid][0][lane] = S;
    part[wvid][1][lane] = A0;
    part[wvid][2][lane] = A1;
    part[wvid][3][lane] = E0;
    part[wvid][4][lane] = E1;
    __syncthreads();
    if (half) return;                      // half-1 waves done (no more barriers)
    S  += part[wvid + 1][0][lane];
    A0 += part[wvid + 1][1][lane];
    A1 += part[wvid + 1][2][lane];
    E0 += part[wvid + 1][3][lane];
    E1 += part[wvid + 1][4][lane];

    // easum post-transform: ep[ch] = sum_j easum[h, j] * we[j, ch], ch = 2l, 2l+1
    sc4[wvid][2 * lane]     = E0;
    sc4[wvid][2 * lane + 1] = E1;
    float ep0 = 0.f, ep1 = 0.f;
    #pragma unroll
    for (int j = 0; j < 16; ++j) {
        float es = sc4[wvid][hb + j];
        ep0 += es * wl[j * 128 + 2 * lane];
        ep1 += es * wl[j * 128 + 2 * lane + 1];
    }

    float rinv = 1.f / (S + 1e-16f);
    float o0 = (A0 + ep0) * rinv;
    float o1 = (A1 + ep1) * rinv;

    uint xrp = *(const uint*)(qkvs + nb + 384 + 2 * lane);
    float xr0 = bf2f((ushort)xrp), xr1 = bf2f((ushort)(xrp >> 16));
    float2 wb0 = *(const float2*)&wbeta[2 * lane];
    float2 wb1 = *(const float2*)&wbeta[128 + 2 * lane];
    float2 wb2 = *(const float2*)&wbeta[256 + 2 * lane];
    float dot = o0 * wb0.x + o1 * wb0.y + xr0 * wb1.x + xr1 * wb1.y
              + (o0 - xr0) * wb2.x + (o1 - xr1) * wb2.y;
    #pragma unroll
    for (int w = 32; w > 0; w >>= 1) dot += __shfl_xor(dot, w, 64);
    float beta = 1.f / (1.f + __expf(-dot));

    size_t xb = (size_t)node * D_MODEL + 2 * lane;
    float2 xv = *(const float2*)&x[xb];
    float ox = xv.x + beta * xr0 + (1.f - beta) * o0;
    float oy = xv.y + beta * xr1 + (1.f - beta) * o1;
    *(float2*)&xnew[xb] = make_float2(ox, oy);

    // ---- fused LN2 (values live in wave registers) ----
    float s2  = ox + oy;
    float ss2 = ox * ox + oy * oy;
    #pragma unroll
    for (int w = 32; w > 0; w >>= 1) {
        s2  += __shfl_xor(s2,  w, 64);
        ss2 += __shfl_xor(ss2, w, 64);
    }
    float mu  = s2 * (1.0f / 128.0f);
    float var = ss2 * (1.0f / 128.0f) - mu * mu;
    float rs  = rsqrtf(var + 1e-5f);
    float2 g2 = *(const float2*)&ln2g[2 * lane];
    float2 b2 = *(const float2*)&ln2b[2 * lane];
    float h0 = (ox - mu) * rs * g2.x + b2.x;
    float h1 = (oy - mu) * rs * g2.y + b2.y;
    ((uint*)h2)[(size_t)node * 64 + lane] = pack2(h0, h1);
}

extern "C" void kernel_launch(void* const* d_in, const int* in_sizes, int n_in,
                              void* d_out, int out_size, void* d_ws, size_t ws_size,
                              hipStream_t stream)
{
    const float* x     = (const float*)d_in[0];
    const int*   eidx  = (const int*)  d_in[1];
    const float* eattr = (const float*)d_in[2];
    const float* wq  = (const float*)d_in[3];  const float* bq  = (const float*)d_in[4];
    const float* wk  = (const float*)d_in[5];  const float* bk  = (const float*)d_in[6];
    const float* wv  = (const float*)d_in[7];  const float* bv  = (const float*)d_in[8];
    const float* we  = (const float*)d_in[9];
    const float* wsk = (const float*)d_in[10]; const float* bsk = (const float*)d_in[11];
    const float* wbeta = (const float*)d_in[12];
    const float* ln1g = (const float*)d_in[13]; const float* ln1b = (const float*)d_in[14];
    const float* ln2g = (const float*)d_in[15]; const float* ln2b = (const float*)d_in[16];
    const float* w1 = (const float*)d_in[17]; const float* b1 = (const float*)d_in[18];
    const float* w2 = (const float*)d_in[19]; const float* b2 = (const float*)d_in[20];
    const int* srcp = eidx;
    const int* dstp = eidx + N_EDGES;
    float* out = (float*)d_out;

    char* w = (char*)d_ws;
    size_t o = 0;
    ushort* qkvs_b  = (ushort*)(w + o);                 // [N][512] bf16 q|k|v|xr
    ushort* hidden_b = qkvs_b;                          // alias: [N][256] bf16 (after attn)
    o += (size_t)N_NODES * 512 * 2;
    float* xnew = (float*)(w + o);  o += (size_t)N_NODES * 128 * 4;
    ushort* eattr_s = (ushort*)(w + o); o += (size_t)N_EDGES * E_DIM * 2;  // bf16, 25.6MB
    int* src_s = (int*)(w + o);     o += (size_t)N_EDGES * 4;
    ushort* xn_b = (ushort*)(w + o);
    ushort* h2_b = xn_b;                                 // alias (LN1 out dead after proj)
    o += (size_t)N_NODES * 128 * 2;
    ushort* wqkvsT = (ushort*)(w + o); o += 512 * 128 * 2;
    ushort* w1T    = (ushort*)(w + o); o += 256 * 128 * 2;
    ushort* w2T    = (ushort*)(w + o); o += 128 * 256 * 2;
    float*  bqkvs  = (float*)(w + o);  o += 4096;
    int* deg    = (int*)(w + o); o += 200704;
    int* offb   = (int*)(w + o); o += 200704;
    int* cursor = (int*)(w + o); o += 200704;
    int* bsum   = (int*)(w + o); o += 4096;

    dim3 blk(256);
    dim3 blk512(512);
    dim3 lngrid((N_NODES + 3) / 4);
    const int NB = (N_NODES + 255) / 256;
    const int EB = (N_EDGES + 255) / 256;
    const int GB = (N_NODES + 127) / 128;

    prep_weights<<<dim3(256), blk, 0, stream>>>(wq, wk, wv, wsk, bq, bk, bv, bsk,
                                                w1, w2, wqkvsT, bqkvs, w1T, w2T);
    ln_kernel<<<lngrid, blk, 0, stream>>>(x, ln1g, ln1b, xn_b, N_NODES);
    mfma_gemm<<<dim3(GB, 8), blk, 0, stream>>>(xn_b, wqkvsT, bqkvs, nullptr,
                                               qkvs_b, N_NODES, 128, 512, 0, 0);
    hipMemsetAsync(deg, 0, (size_t)N_NODES * 4, stream);
    hist_kernel<<<dim3(EB), blk, 0, stream>>>(dstp, deg);
    scan1_kernel<<<dim3(NB), blk, 0, stream>>>(deg, offb, bsum);
    scan2_kernel<<<dim3(1), blk, 0, stream>>>(bsum, NB);
    scan3_kernel<<<dim3(NB), blk, 0, stream>>>(offb, bsum, cursor);
    scatter_kernel<<<dim3(EB), blk, 0, stream>>>(dstp, srcp, eattr, cursor, src_s, eattr_s);
    node_attn<<<lngrid, blk512, 0, stream>>>(qkvs_b, x, we, wbeta, ln2g, ln2b,
                                             offb, deg, src_s, eattr_s, xnew, h2_b);
    mfma_gemm<<<dim3(GB, 4), blk, 0, stream>>>(h2_b, w1T, b1, nullptr,
                                               hidden_b, N_NODES, 128, 256, 1, 0);
    mfma_gemm<<<dim3(GB, 2), blk, 0, stream>>>(hidden_b, w2T, b2, xnew,
                                               out, N_NODES, 256, 128, 0, 1);
}

// Round 11
// 320.521 us; speedup vs baseline: 1.1006x; 1.1006x over previous
//
#include <hip/hip_runtime.h>
#include <math.h>

#define N_NODES 50000
#define D_MODEL 128
#define N_HEADS 8
#define HEAD_C 16
#define E_DIM 16
#define N_EDGES 800000

typedef __attribute__((ext_vector_type(8))) short bf16x8;
typedef __attribute__((ext_vector_type(4))) float f32x4;

__device__ inline ushort f2bf(float f) {
    unsigned u = __float_as_uint(f);
    unsigned r = (u + 0x7fffu + ((u >> 16) & 1u)) >> 16;
    return (ushort)r;
}
__device__ inline float bf2f(ushort h) { return __uint_as_float(((unsigned)h) << 16); }
__device__ inline uint pack2(float a, float b) {
    return (uint)f2bf(a) | ((uint)f2bf(b) << 16);
}
__device__ inline float gelu_f(float v) {
    return 0.5f * v * (1.0f + erff(v * 0.70710678118654752f));
}

// ---------------- Weight prep: transpose + bf16 cast ----------------
__global__ void prep_weights(const float* __restrict__ wq, const float* __restrict__ wk,
                             const float* __restrict__ wv, const float* __restrict__ wsk,
                             const float* __restrict__ bq, const float* __restrict__ bk,
                             const float* __restrict__ bv, const float* __restrict__ bsk,
                             const float* __restrict__ w1, const float* __restrict__ w2,
                             ushort* __restrict__ wqkvsT, float* __restrict__ bqkvs,
                             ushort* __restrict__ w1T, ushort* __restrict__ w2T)
{
    int idx = blockIdx.x * 256 + threadIdx.x;          // 0..65535
    {   // wqkvsT [512][128] <- {wq|wk|wv|wsk}[128][128] transposed
        int m = idx >> 7, kk = idx & 127;
        int b = m >> 7, ch = m & 127;
        const float* src = (b == 0) ? wq : (b == 1) ? wk : (b == 2) ? wv : wsk;
        wqkvsT[idx] = f2bf(src[kk * 128 + ch]);
    }
    if (idx < 256 * 128) {   // w1T [256][128] <- w1[128][256]
        int m = idx >> 7, k = idx & 127;
        w1T[idx] = f2bf(w1[k * 256 + m]);
    }
    if (idx < 128 * 256) {   // w2T [128][256] <- w2[256][128]
        int m = idx >> 8, k = idx & 255;
        w2T[idx] = f2bf(w2[k * 128 + m]);
    }
    if (idx < 512) {
        int b = idx >> 7, ch = idx & 127;
        const float* bb = (b == 0) ? bq : (b == 1) ? bk : (b == 2) ? bv : bsk;
        bqkvs[idx] = bb[ch];
    }
}

// ---------------- Fused LN1 + projection GEMM (K=128, M=512, BN=64) ----------------
// A-tile stages FULL rows, so LN1 is computed in the staging loop: thread t's
// chunk c = t + i*256 always has col16 = t&15 (256 % 16 == 0) and row group
// spans 16 aligned lanes -> shfl_xor reduction over masks 1,2,4,8.
__global__ __launch_bounds__(256) void proj_ln_gemm(
    const float* __restrict__ X, const float* __restrict__ ln_g, const float* __restrict__ ln_b,
    const ushort* __restrict__ WT, const float* __restrict__ bias,
    ushort* __restrict__ Y, int nrows)
{
    __shared__ __align__(16) ushort Al[128 * 128];   // 32 KB
    __shared__ __align__(16) ushort Wl[64 * 128];    // 16 KB
    int tid = threadIdx.x;
    int wv = tid >> 6, lane = tid & 63;
    int row0 = blockIdx.x * 128;
    int col0 = blockIdx.y * 64;

    // hoisted: this thread's fixed 8-col slice of gamma/beta
    int c16 = tid & 15;
    float4 g0 = *(const float4*)&ln_g[c16 * 8];
    float4 g1 = *(const float4*)&ln_g[c16 * 8 + 4];
    float4 bb0 = *(const float4*)&ln_b[c16 * 8];
    float4 bb1 = *(const float4*)&ln_b[c16 * 8 + 4];

    // stage A with fused LN1
    #pragma unroll
    for (int i = 0; i < 8; ++i) {
        int c = tid + i * 256;
        int r = c >> 4;
        int gr = row0 + r;
        float4 xa = make_float4(0.f, 0.f, 0.f, 0.f), xb = xa;
        if (gr < nrows) {
            xa = *(const float4*)&X[(size_t)gr * 128 + c16 * 8];
            xb = *(const float4*)&X[(size_t)gr * 128 + c16 * 8 + 4];
        }
        float s  = xa.x + xa.y + xa.z + xa.w + xb.x + xb.y + xb.z + xb.w;
        float ss = xa.x*xa.x + xa.y*xa.y + xa.z*xa.z + xa.w*xa.w
                 + xb.x*xb.x + xb.y*xb.y + xb.z*xb.z + xb.w*xb.w;
        #pragma unroll
        for (int m = 1; m < 16; m <<= 1) {
            s  += __shfl_xor(s,  m, 64);
            ss += __shfl_xor(ss, m, 64);
        }
        float mu  = s * (1.0f / 128.0f);
        float var = ss * (1.0f / 128.0f) - mu * mu;
        float rs  = rsqrtf(var + 1e-5f);
        ushort h[8];
        h[0] = f2bf((xa.x - mu) * rs * g0.x + bb0.x);
        h[1] = f2bf((xa.y - mu) * rs * g0.y + bb0.y);
        h[2] = f2bf((xa.z - mu) * rs * g0.z + bb0.z);
        h[3] = f2bf((xa.w - mu) * rs * g0.w + bb0.w);
        h[4] = f2bf((xb.x - mu) * rs * g1.x + bb1.x);
        h[5] = f2bf((xb.y - mu) * rs * g1.y + bb1.y);
        h[6] = f2bf((xb.z - mu) * rs * g1.z + bb1.z);
        h[7] = f2bf((xb.w - mu) * rs * g1.w + bb1.w);
        int byte = r * 256 + ((c16 * 16) ^ ((r & 7) << 4));
        *(ulonglong2*)((char*)Al + byte) = *(ulonglong2*)h;
    }
    // stage W tile [64 cols][128 k]
    #pragma unroll
    for (int i = 0; i < 4; ++i) {
        int c = tid + i * 256;
        int r = c >> 4, cc = c & 15;
        ulonglong2 val = *(const ulonglong2*)(WT + (size_t)(col0 + r) * 128 + cc * 8);
        int byte = r * 256 + ((cc * 16) ^ ((r & 7) << 4));
        *(ulonglong2*)((char*)Wl + byte) = val;
    }
    __syncthreads();

    f32x4 acc[2][4];
    #pragma unroll
    for (int i = 0; i < 2; ++i)
        #pragma unroll
        for (int j = 0; j < 4; ++j) acc[i][j] = (f32x4){0.f, 0.f, 0.f, 0.f};
    #pragma unroll
    for (int ks = 0; ks < 4; ++ks) {
        bf16x8 af[2], bfr[4];
        #pragma unroll
        for (int rt = 0; rt < 2; ++rt) {
            int r = wv * 32 + rt * 16 + (lane & 15);
            int byte = r * 256 + ((ks * 64 + (lane >> 4) * 16) ^ ((r & 7) << 4));
            af[rt] = *(const bf16x8*)((const char*)Al + byte);
        }
        #pragma unroll
        for (int ct = 0; ct < 4; ++ct) {
            int r = ct * 16 + (lane & 15);
            int byte = r * 256 + ((ks * 64 + (lane >> 4) * 16) ^ ((r & 7) << 4));
            bfr[ct] = *(const bf16x8*)((const char*)Wl + byte);
        }
        #pragma unroll
        for (int rt = 0; rt < 2; ++rt)
            #pragma unroll
            for (int ct = 0; ct < 4; ++ct)
                acc[rt][ct] = __builtin_amdgcn_mfma_f32_16x16x32_bf16(
                    af[rt], bfr[ct], acc[rt][ct], 0, 0, 0);
    }
    #pragma unroll
    for (int rt = 0; rt < 2; ++rt) {
        #pragma unroll
        for (int ct = 0; ct < 4; ++ct) {
            int gcol = col0 + ct * 16 + (lane & 15);
            float bv = bias[gcol];
            #pragma unroll
            for (int r = 0; r < 4; ++r) {
                int grow = row0 + wv * 32 + rt * 16 + (lane >> 4) * 4 + r;
                if (grow >= nrows) continue;
                Y[(size_t)grow * 512 + gcol] = f2bf(acc[rt][ct][r] + bv);
            }
        }
    }
}

// ---------------- Fused FFN: out = xnew + (gelu(h2@W1+b1))@W2 + b2 ----------------
// 128 KB LDS: Xl 32K (A tile) + Wl 32K (restaged 4x: W1a,W1b,W2a,W2b) + Hl 64K
// (hidden, 512B row stride, 16B-chunk XOR swizzle -> 2-way-free fragment reads).
__global__ __launch_bounds__(256) void ffn_fused(
    const ushort* __restrict__ A, const ushort* __restrict__ W1T,
    const ushort* __restrict__ W2T, const float* __restrict__ b1,
    const float* __restrict__ b2, const float* __restrict__ xnew,
    float* __restrict__ out, int nrows)
{
    __shared__ __align__(16) ushort Xl[128 * 128];   // 32 KB
    __shared__ __align__(16) ushort Wl[64 * 256];    // 32 KB (viewed per-phase)
    __shared__ __align__(16) ushort Hl[128 * 256];   // 64 KB
    int tid = threadIdx.x;
    int wv = tid >> 6, lane = tid & 63;
    int row0 = blockIdx.x * 128;

    // stage Xl (h2 rows)
    #pragma unroll
    for (int i = 0; i < 8; ++i) {
        int c = tid + i * 256;
        int r = c >> 4, c16 = c & 15;
        int gr = row0 + r;
        ulonglong2 val = {0ull, 0ull};
        if (gr < nrows) val = *(const ulonglong2*)(A + (size_t)gr * 128 + c16 * 8);
        int byte = r * 256 + ((c16 * 16) ^ ((r & 7) << 4));
        *(ulonglong2*)((char*)Xl + byte) = val;
    }

    // ---- GEMM1 in two 128-col halves ----
    for (int h = 0; h < 2; ++h) {
        // stage Wl = W1T rows [h*128, h*128+128), layout [128][128]
        #pragma unroll
        for (int i = 0; i < 8; ++i) {
            int c = tid + i * 256;
            int r = c >> 4, c16 = c & 15;
            ulonglong2 val = *(const ulonglong2*)(W1T + (size_t)(h * 128 + r) * 128 + c16 * 8);
            int byte = r * 256 + ((c16 * 16) ^ ((r & 7) << 4));
            *(ulonglong2*)((char*)Wl + byte) = val;
        }
        __syncthreads();
        f32x4 acc1[2][8];
        #pragma unroll
        for (int i = 0; i < 2; ++i)
            #pragma unroll
            for (int j = 0; j < 8; ++j) acc1[i][j] = (f32x4){0.f, 0.f, 0.f, 0.f};
        #pragma unroll
        for (int ks = 0; ks < 4; ++ks) {
            bf16x8 af[2], bfr[8];
            #pragma unroll
            for (int rt = 0; rt < 2; ++rt) {
                int r = wv * 32 + rt * 16 + (lane & 15);
                int byte = r * 256 + ((ks * 64 + (lane >> 4) * 16) ^ ((r & 7) << 4));
                af[rt] = *(const bf16x8*)((const char*)Xl + byte);
            }
            #pragma unroll
            for (int ct = 0; ct < 8; ++ct) {
                int r = ct * 16 + (lane & 15);
                int byte = r * 256 + ((ks * 64 + (lane >> 4) * 16) ^ ((r & 7) << 4));
                bfr[ct] = *(const bf16x8*)((const char*)Wl + byte);
            }
            #pragma unroll
            for (int rt = 0; rt < 2; ++rt)
                #pragma unroll
                for (int ct = 0; ct < 8; ++ct)
                    acc1[rt][ct] = __builtin_amdgcn_mfma_f32_16x16x32_bf16(
                        af[rt], bfr[ct], acc1[rt][ct], 0, 0, 0);
        }
        // bias + gelu -> hidden in Hl (swizzled 16B chunks, row stride 512B)
        #pragma unroll
        for (int rt = 0; rt < 2; ++rt) {
            #pragma unroll
            for (int ct = 0; ct < 8; ++ct) {
                int col = h * 128 + ct * 16 + (lane & 15);
                float bv = b1[col];
                #pragma unroll
                for (int r = 0; r < 4; ++r) {
                    int row = wv * 32 + rt * 16 + (lane >> 4) * 4 + r;
                    float v = gelu_f(acc1[rt][ct][r] + bv);
                    int cb = col * 2;
                    int byte = row * 512 + (((cb) & ~15) ^ ((row & 7) << 4)) + (cb & 15);
                    *(ushort*)((char*)Hl + byte) = f2bf(v);
                }
            }
        }
        __syncthreads();   // Wl consumed + Hl half visible
    }

    // ---- GEMM2 in two 64-outcol halves, K=256 ----
    for (int g = 0; g < 2; ++g) {
        // stage Wl = W2T rows [g*64, g*64+64), layout [64][256] (row stride 512B)
        #pragma unroll
        for (int i = 0; i < 8; ++i) {
            int c = tid + i * 256;
            int r = c >> 5, c32 = c & 31;
            ulonglong2 val = *(const ulonglong2*)(W2T + (size_t)(g * 64 + r) * 256 + c32 * 8);
            int byte = r * 512 + ((c32 * 16) ^ ((r & 7) << 4));
            *(ulonglong2*)((char*)Wl + byte) = val;
        }
        __syncthreads();
        f32x4 acc2[2][4];
        #pragma unroll
        for (int i = 0; i < 2; ++i)
            #pragma unroll
            for (int j = 0; j < 4; ++j) acc2[i][j] = (f32x4){0.f, 0.f, 0.f, 0.f};
        #pragma unroll
        for (int ks = 0; ks < 8; ++ks) {
            bf16x8 af[2], bfr[4];
            #pragma unroll
            for (int rt = 0; rt < 2; ++rt) {
                int row = wv * 32 + rt * 16 + (lane & 15);
                int byte = row * 512 + ((ks * 64 + (lane >> 4) * 16) ^ ((row & 7) << 4));
                af[rt] = *(const bf16x8*)((const char*)Hl + byte);
            }
            #pragma unroll
            for (int ct = 0; ct < 4; ++ct) {
                int r = ct * 16 + (lane & 15);
                int byte = r * 512 + ((ks * 64 + (lane >> 4) * 16) ^ ((r & 7) << 4));
                bfr[ct] = *(const bf16x8*)((const char*)Wl + byte);
            }
            #pragma unroll
            for (int rt = 0; rt < 2; ++rt)
                #pragma unroll
                for (int ct = 0; ct < 4; ++ct)
                    acc2[rt][ct] = __builtin_amdgcn_mfma_f32_16x16x32_bf16(
                        af[rt], bfr[ct], acc2[rt][ct], 0, 0, 0);
        }
        // epilogue: + b2 + xnew residual -> out (f32)
        #pragma unroll
        for (int rt = 0; rt < 2; ++rt) {
            #pragma unroll
            for (int ct = 0; ct < 4; ++ct) {
                int gcol = g * 64 + ct * 16 + (lane & 15);
                float bv = b2[gcol];
                #pragma unroll
                for (int r = 0; r < 4; ++r) {
                    int grow = row0 + wv * 32 + rt * 16 + (lane >> 4) * 4 + r;
                    if (grow >= nrows) continue;
                    size_t idx = (size_t)grow * 128 + gcol;
                    out[idx] = acc2[rt][ct][r] + bv + xnew[idx];
                }
            }
        }
        __syncthreads();   // Wl consumed before restage
    }
}

// ---------------- Counting sort of edges by destination ----------------
__global__ void hist_kernel(const int* __restrict__ dst, int* __restrict__ deg)
{
    int e = blockIdx.x * 256 + threadIdx.x;
    if (e < N_EDGES) atomicAdd(&deg[dst[e]], 1);
}

__global__ void scan1_kernel(const int* __restrict__ deg, int* __restrict__ off,
                             int* __restrict__ bsum)
{
    __shared__ int sm[256];
    int i = blockIdx.x * 256 + threadIdx.x;
    int v = (i < N_NODES) ? deg[i] : 0;
    sm[threadIdx.x] = v;
    __syncthreads();
    #pragma unroll
    for (int d = 1; d < 256; d <<= 1) {
        int t = (threadIdx.x >= d) ? sm[threadIdx.x - d] : 0;
        __syncthreads();
        sm[threadIdx.x] += t;
        __syncthreads();
    }
    if (i < N_NODES) off[i] = sm[threadIdx.x] - v;
    if (threadIdx.x == 255) bsum[blockIdx.x] = sm[255];
}

__global__ void scan2_kernel(int* __restrict__ bsum, int nb)
{
    __shared__ int sm[256];
    int v = (threadIdx.x < nb) ? bsum[threadIdx.x] : 0;
    sm[threadIdx.x] = v;
    __syncthreads();
    #pragma unroll
    for (int d = 1; d < 256; d <<= 1) {
        int t = (threadIdx.x >= d) ? sm[threadIdx.x - d] : 0;
        __syncthreads();
        sm[threadIdx.x] += t;
        __syncthreads();
    }
    if (threadIdx.x < nb) bsum[threadIdx.x] = sm[threadIdx.x] - v;
}

__global__ void scan3_kernel(int* __restrict__ off, const int* __restrict__ bsum,
                             int* __restrict__ cursor)
{
    int i = blockIdx.x * 256 + threadIdx.x;
    if (i < N_NODES) {
        int o = off[i] + bsum[blockIdx.x];
        off[i] = o;
        cursor[i] = o;
    }
}

// scatter: src id + bf16 edge_attr row in destination-sorted order
// (random writes here buy SEQUENTIAL hot-loop reads in node_attn — r6 lesson)
__global__ void scatter_kernel(const int* __restrict__ dst, const int* __restrict__ src,
                               const float* __restrict__ eattr, int* __restrict__ cursor,
                               int* __restrict__ src_s, ushort* __restrict__ eattr_s)
{
    int e = blockIdx.x * 256 + threadIdx.x;
    if (e < N_EDGES) {
        int p = atomicAdd(&cursor[dst[e]], 1);
        src_s[p] = src[e];
        const float4* s4 = (const float4*)(eattr + (size_t)e * E_DIM);
        float4 f0 = s4[0], f1 = s4[1], f2 = s4[2], f3 = s4[3];
        uint4 u0, u1;
        u0.x = pack2(f0.x, f0.y); u0.y = pack2(f0.z, f0.w);
        u0.z = pack2(f1.x, f1.y); u0.w = pack2(f1.z, f1.w);
        u1.x = pack2(f2.x, f2.y); u1.y = pack2(f2.z, f2.w);
        u1.z = pack2(f3.x, f3.y); u1.w = pack2(f3.z, f3.w);
        uint4* d4 = (uint4*)(eattr_s + (size_t)p * E_DIM);
        d4[0] = u0; d4[1] = u1;
    }
}

// ---------------- Fused node attention (r9 EXACT) + beta + residual + LN2 ----------
// Lane l owns head h = l>>3, channels 2l, 2l+1 (j = l&7 -> ea comps 2j, 2j+1).
// 2-way unroll with DUAL accumulator state (r8/r10 lessons: do not restructure).
#define ATTN_STEP(P, S, A0, A1, E0, E1) do {                                         \
    int sv_ = src_s[P];                                                              \
    uint eap_ = *(const uint*)(eattr_s + (size_t)(P) * E_DIM + j2);                  \
    float ea0_ = bf2f((ushort)eap_), ea1_ = bf2f((ushort)(eap_ >> 16));              \
    size_t sb_ = (size_t)sv_ * 512;                                                  \
    uint kp_ = *(const uint*)(qkvs + sb_ + 128 + 2 * lane);                          \
    uint vp_ = *(const uint*)(qkvs + sb_ + 256 + 2 * lane);                          \
    float p_ = q0 * bf2f((ushort)kp_) + q1 * bf2f((ushort)(kp_ >> 16))               \
             + ea0_ * qp0 + ea1_ * qp1;                                              \
    p_ += __shfl_xor(p_, 1, 64);                                                     \
    p_ += __shfl_xor(p_, 2, 64);                                                     \
    p_ += __shfl_xor(p_, 4, 64);                                                     \
    float w_ = __expf(fminf(p_, 60.f));                                              \
    S  += w_;                                                                        \
    A0 += w_ * bf2f((ushort)vp_);                                                    \
    A1 += w_ * bf2f((ushort)(vp_ >> 16));                                            \
    E0 += w_ * ea0_;                                                                 \
    E1 += w_ * ea1_;                                                                 \
} while (0)

__global__ void node_attn(const ushort* __restrict__ qkvs, const float* __restrict__ x,
                          const float* __restrict__ we, const float* __restrict__ wbeta,
                          const float* __restrict__ ln2g, const float* __restrict__ ln2b,
                          const int* __restrict__ off, const int* __restrict__ deg,
                          const int* __restrict__ src_s, const ushort* __restrict__ eattr_s,
                          float* __restrict__ xnew, ushort* __restrict__ h2)
{
    __shared__ float wl[E_DIM * 128];     // we row-major [16][128], 8 KB
    __shared__ float weT[128 * 17];       // we transposed [128][16+pad], 8.5 KB
    __shared__ float sc4[4][128];         // per-wave scratch, 2 KB
    for (int t = threadIdx.x; t < E_DIM * 32; t += 256)
        *(float4*)&wl[t * 4] = *(const float4*)&we[t * 4];
    for (int t = threadIdx.x; t < E_DIM * 128; t += 256) {
        int j = t >> 7, ch = t & 127;
        weT[ch * 17 + j] = we[t];
    }
    __syncthreads();

    int nl   = threadIdx.x >> 6;
    int node = blockIdx.x * 4 + nl;
    int lane = threadIdx.x & 63;
    if (node >= N_NODES) return;

    int j2 = (lane & 7) * 2;              // this lane's ea component pair
    int hb = (lane >> 3) * 16;            // head channel base

    size_t nb = (size_t)node * 512;
    uint qp = *(const uint*)(qkvs + nb + 2 * lane);
    float q0r = bf2f((ushort)qp), q1r = bf2f((ushort)(qp >> 16));

    sc4[nl][2 * lane]     = q0r;
    sc4[nl][2 * lane + 1] = q1r;
    float qp0 = 0.f, qp1 = 0.f;
    #pragma unroll
    for (int c = 0; c < 16; ++c) {
        float qc = sc4[nl][hb + c];
        qp0 += qc * weT[(hb + c) * 17 + j2];
        qp1 += qc * weT[(hb + c) * 17 + j2 + 1];
    }
    float q0 = q0r * 0.25f, q1 = q1r * 0.25f;   // fold 1/sqrt(C)
    qp0 *= 0.25f; qp1 *= 0.25f;

    float SA = 0.f, A0a = 0.f, A1a = 0.f, E0a = 0.f, E1a = 0.f;
    float SB = 0.f, A0b = 0.f, A1b = 0.f, E0b = 0.f, E1b = 0.f;

    int o = off[node], dg = deg[node];
    int i = 0;
    for (; i + 2 <= dg; i += 2) {
        ATTN_STEP(o + i,     SA, A0a, A1a, E0a, E1a);
        ATTN_STEP(o + i + 1, SB, A0b, A1b, E0b, E1b);
    }
    if (i < dg)
        ATTN_STEP(o + i, SA, A0a, A1a, E0a, E1a);

    float S  = SA + SB;
    float A0 = A0a + A0b, A1 = A1a + A1b;
    float E0 = E0a + E0b, E1 = E1a + E1b;

    sc4[nl][2 * lane]     = E0;
    sc4[nl][2 * lane + 1] = E1;
    float ep0 = 0.f, ep1 = 0.f;
    #pragma unroll
    for (int j = 0; j < 16; ++j) {
        float es = sc4[nl][hb + j];
        ep0 += es * wl[j * 128 + 2 * lane];
        ep1 += es * wl[j * 128 + 2 * lane + 1];
    }

    float rinv = 1.f / (S + 1e-16f);
    float o0 = (A0 + ep0) * rinv;
    float o1 = (A1 + ep1) * rinv;

    uint xrp = *(const uint*)(qkvs + nb + 384 + 2 * lane);
    float xr0 = bf2f((ushort)xrp), xr1 = bf2f((ushort)(xrp >> 16));
    float2 wb0 = *(const float2*)&wbeta[2 * lane];
    float2 wb1 = *(const float2*)&wbeta[128 + 2 * lane];
    float2 wb2 = *(const float2*)&wbeta[256 + 2 * lane];
    float dot = o0 * wb0.x + o1 * wb0.y + xr0 * wb1.x + xr1 * wb1.y
              + (o0 - xr0) * wb2.x + (o1 - xr1) * wb2.y;
    #pragma unroll
    for (int w = 32; w > 0; w >>= 1) dot += __shfl_xor(dot, w, 64);
    float beta = 1.f / (1.f + __expf(-dot));

    size_t xb = (size_t)node * D_MODEL + 2 * lane;
    float2 xv = *(const float2*)&x[xb];
    float ox = xv.x + beta * xr0 + (1.f - beta) * o0;
    float oy = xv.y + beta * xr1 + (1.f - beta) * o1;
    *(float2*)&xnew[xb] = make_float2(ox, oy);

    // ---- fused LN2 ----
    float s2  = ox + oy;
    float ss2 = ox * ox + oy * oy;
    #pragma unroll
    for (int w = 32; w > 0; w >>= 1) {
        s2  += __shfl_xor(s2,  w, 64);
        ss2 += __shfl_xor(ss2, w, 64);
    }
    float mu  = s2 * (1.0f / 128.0f);
    float var = ss2 * (1.0f / 128.0f) - mu * mu;
    float rs  = rsqrtf(var + 1e-5f);
    float2 g2 = *(const float2*)&ln2g[2 * lane];
    float2 b2 = *(const float2*)&ln2b[2 * lane];
    float h0 = (ox - mu) * rs * g2.x + b2.x;
    float h1 = (oy - mu) * rs * g2.y + b2.y;
    ((uint*)h2)[(size_t)node * 64 + lane] = pack2(h0, h1);
}

extern "C" void kernel_launch(void* const* d_in, const int* in_sizes, int n_in,
                              void* d_out, int out_size, void* d_ws, size_t ws_size,
                              hipStream_t stream)
{
    const float* x     = (const float*)d_in[0];
    const int*   eidx  = (const int*)  d_in[1];
    const float* eattr = (const float*)d_in[2];
    const float* wq  = (const float*)d_in[3];  const float* bq  = (const float*)d_in[4];
    const float* wk  = (const float*)d_in[5];  const float* bk  = (const float*)d_in[6];
    const float* wv  = (const float*)d_in[7];  const float* bv  = (const float*)d_in[8];
    const float* we  = (const float*)d_in[9];
    const float* wsk = (const float*)d_in[10]; const float* bsk = (const float*)d_in[11];
    const float* wbeta = (const float*)d_in[12];
    const float* ln1g = (const float*)d_in[13]; const float* ln1b = (const float*)d_in[14];
    const float* ln2g = (const float*)d_in[15]; const float* ln2b = (const float*)d_in[16];
    const float* w1 = (const float*)d_in[17]; const float* b1 = (const float*)d_in[18];
    const float* w2 = (const float*)d_in[19]; const float* b2 = (const float*)d_in[20];
    const int* srcp = eidx;
    const int* dstp = eidx + N_EDGES;
    float* out = (float*)d_out;

    char* w = (char*)d_ws;
    size_t o = 0;
    ushort* qkvs_b  = (ushort*)(w + o);  o += (size_t)N_NODES * 512 * 2;   // 51.2MB
    float* xnew = (float*)(w + o);  o += (size_t)N_NODES * 128 * 4;        // 25.6MB
    ushort* eattr_s = (ushort*)(w + o); o += (size_t)N_EDGES * E_DIM * 2;  // 25.6MB
    int* src_s = (int*)(w + o);     o += (size_t)N_EDGES * 4;              // 3.2MB
    ushort* h2_b = (ushort*)(w + o); o += (size_t)N_NODES * 128 * 2;       // 12.8MB
    ushort* wqkvsT = (ushort*)(w + o); o += 512 * 128 * 2;
    ushort* w1T    = (ushort*)(w + o); o += 256 * 128 * 2;
    ushort* w2T    = (ushort*)(w + o); o += 128 * 256 * 2;
    float*  bqkvs  = (float*)(w + o);  o += 4096;
    int* deg    = (int*)(w + o); o += 200704;
    int* offb   = (int*)(w + o); o += 200704;
    int* cursor = (int*)(w + o); o += 200704;
    int* bsum   = (int*)(w + o); o += 4096;

    dim3 blk(256);
    dim3 lngrid((N_NODES + 3) / 4);
    const int NB = (N_NODES + 255) / 256;
    const int EB = (N_EDGES + 255) / 256;
    const int GB = (N_NODES + 127) / 128;

    prep_weights<<<dim3(256), blk, 0, stream>>>(wq, wk, wv, wsk, bq, bk, bv, bsk,
                                                w1, w2, wqkvsT, bqkvs, w1T, w2T);
    // fused LN1 + projections -> qkvs bf16 [N][512]
    proj_ln_gemm<<<dim3(GB, 8), blk, 0, stream>>>(x, ln1g, ln1b, wqkvsT, bqkvs,
                                                  qkvs_b, N_NODES);
    hipMemsetAsync(deg, 0, (size_t)N_NODES * 4, stream);
    hist_kernel<<<dim3(EB), blk, 0, stream>>>(dstp, deg);
    scan1_kernel<<<dim3(NB), blk, 0, stream>>>(deg, offb, bsum);
    scan2_kernel<<<dim3(1), blk, 0, stream>>>(bsum, NB);
    scan3_kernel<<<dim3(NB), blk, 0, stream>>>(offb, bsum, cursor);
    scatter_kernel<<<dim3(EB), blk, 0, stream>>>(dstp, srcp, eattr, cursor, src_s, eattr_s);
    node_attn<<<lngrid, blk, 0, stream>>>(qkvs_b, x, we, wbeta, ln2g, ln2b,
                                          offb, deg, src_s, eattr_s, xnew, h2_b);
    // fused FFN1+FFN2 (+ residual) -> d_out
    ffn_fused<<<dim3(GB), blk, 0, stream>>>(h2_b, w1T, w2T, b1, b2, xnew, out, N_NODES);
}

// Round 12
// 291.976 us; speedup vs baseline: 1.2082x; 1.0978x over previous
//
#include <hip/hip_runtime.h>
#include <math.h>

#define N_NODES 50000
#define D_MODEL 128
#define N_HEADS 8
#define HEAD_C 16
#define E_DIM 16
#define N_EDGES 800000

typedef __attribute__((ext_vector_type(8))) short bf16x8;
typedef __attribute__((ext_vector_type(4))) float f32x4;

__device__ inline ushort f2bf(float f) {
    unsigned u = __float_as_uint(f);
    unsigned r = (u + 0x7fffu + ((u >> 16) & 1u)) >> 16;
    return (ushort)r;
}
__device__ inline float bf2f(ushort h) { return __uint_as_float(((unsigned)h) << 16); }
__device__ inline uint pack2(float a, float b) {
    return (uint)f2bf(a) | ((uint)f2bf(b) << 16);
}
__device__ inline float gelu_f(float v) {
    return 0.5f * v * (1.0f + erff(v * 0.70710678118654752f));
}

// ---------------- Weight prep: transpose + bf16 cast (+ zero deg) ----------------
__global__ void prep_weights(const float* __restrict__ wq, const float* __restrict__ wk,
                             const float* __restrict__ wv, const float* __restrict__ wsk,
                             const float* __restrict__ bq, const float* __restrict__ bk,
                             const float* __restrict__ bv, const float* __restrict__ bsk,
                             const float* __restrict__ w1, const float* __restrict__ w2,
                             ushort* __restrict__ wqkvsT, float* __restrict__ bqkvs,
                             ushort* __restrict__ w1T, ushort* __restrict__ w2T,
                             int* __restrict__ deg)
{
    int idx = blockIdx.x * 256 + threadIdx.x;          // 0..65535
    {   // wqkvsT [512][128] <- {wq|wk|wv|wsk}[128][128] transposed
        int m = idx >> 7, kk = idx & 127;
        int b = m >> 7, ch = m & 127;
        const float* src = (b == 0) ? wq : (b == 1) ? wk : (b == 2) ? wv : wsk;
        wqkvsT[idx] = f2bf(src[kk * 128 + ch]);
    }
    if (idx < 256 * 128) {   // w1T [256][128] <- w1[128][256]
        int m = idx >> 7, k = idx & 127;
        w1T[idx] = f2bf(w1[k * 256 + m]);
    }
    if (idx < 128 * 256) {   // w2T [128][256] <- w2[256][128]
        int m = idx >> 8, k = idx & 255;
        w2T[idx] = f2bf(w2[k * 128 + m]);
    }
    if (idx < 512) {
        int b = idx >> 7, ch = idx & 127;
        const float* bb = (b == 0) ? bq : (b == 1) ? bk : (b == 2) ? bv : bsk;
        bqkvs[idx] = bb[ch];
    }
    if (idx < N_NODES) deg[idx] = 0;   // replaces hipMemsetAsync dispatch
}

// ---------------- Fused LN1 + projection GEMM (K=128, M=512, BN=128) ----------------
// A-tile stages FULL rows so LN1 is computed in the staging loop (16-lane shfl
// reduction). BN=128 halves A re-reads vs BN=64 (4 col-tiles instead of 8).
__global__ __launch_bounds__(256) void proj_ln_gemm(
    const float* __restrict__ X, const float* __restrict__ ln_g, const float* __restrict__ ln_b,
    const ushort* __restrict__ WT, const float* __restrict__ bias,
    ushort* __restrict__ Y, int nrows)
{
    __shared__ __align__(16) ushort Al[128 * 128];   // 32 KB
    __shared__ __align__(16) ushort Wl[128 * 128];   // 32 KB
    int tid = threadIdx.x;
    int wv = tid >> 6, lane = tid & 63;
    int row0 = blockIdx.x * 128;
    int col0 = blockIdx.y * 128;

    int c16 = tid & 15;
    float4 g0 = *(const float4*)&ln_g[c16 * 8];
    float4 g1 = *(const float4*)&ln_g[c16 * 8 + 4];
    float4 bb0 = *(const float4*)&ln_b[c16 * 8];
    float4 bb1 = *(const float4*)&ln_b[c16 * 8 + 4];

    // stage A with fused LN1
    #pragma unroll
    for (int i = 0; i < 8; ++i) {
        int c = tid + i * 256;
        int r = c >> 4;
        int gr = row0 + r;
        float4 xa = make_float4(0.f, 0.f, 0.f, 0.f), xb = xa;
        if (gr < nrows) {
            xa = *(const float4*)&X[(size_t)gr * 128 + c16 * 8];
            xb = *(const float4*)&X[(size_t)gr * 128 + c16 * 8 + 4];
        }
        float s  = xa.x + xa.y + xa.z + xa.w + xb.x + xb.y + xb.z + xb.w;
        float ss = xa.x*xa.x + xa.y*xa.y + xa.z*xa.z + xa.w*xa.w
                 + xb.x*xb.x + xb.y*xb.y + xb.z*xb.z + xb.w*xb.w;
        #pragma unroll
        for (int m = 1; m < 16; m <<= 1) {
            s  += __shfl_xor(s,  m, 64);
            ss += __shfl_xor(ss, m, 64);
        }
        float mu  = s * (1.0f / 128.0f);
        float var = ss * (1.0f / 128.0f) - mu * mu;
        float rs  = rsqrtf(var + 1e-5f);
        ushort h[8];
        h[0] = f2bf((xa.x - mu) * rs * g0.x + bb0.x);
        h[1] = f2bf((xa.y - mu) * rs * g0.y + bb0.y);
        h[2] = f2bf((xa.z - mu) * rs * g0.z + bb0.z);
        h[3] = f2bf((xa.w - mu) * rs * g0.w + bb0.w);
        h[4] = f2bf((xb.x - mu) * rs * g1.x + bb1.x);
        h[5] = f2bf((xb.y - mu) * rs * g1.y + bb1.y);
        h[6] = f2bf((xb.z - mu) * rs * g1.z + bb1.z);
        h[7] = f2bf((xb.w - mu) * rs * g1.w + bb1.w);
        int byte = r * 256 + ((c16 * 16) ^ ((r & 7) << 4));
        *(ulonglong2*)((char*)Al + byte) = *(ulonglong2*)h;
    }
    // stage W tile [128 cols][128 k]
    #pragma unroll
    for (int i = 0; i < 8; ++i) {
        int c = tid + i * 256;
        int r = c >> 4, cc = c & 15;
        ulonglong2 val = *(const ulonglong2*)(WT + (size_t)(col0 + r) * 128 + cc * 8);
        int byte = r * 256 + ((cc * 16) ^ ((r & 7) << 4));
        *(ulonglong2*)((char*)Wl + byte) = val;
    }
    __syncthreads();

    f32x4 acc[2][8];
    #pragma unroll
    for (int i = 0; i < 2; ++i)
        #pragma unroll
        for (int j = 0; j < 8; ++j) acc[i][j] = (f32x4){0.f, 0.f, 0.f, 0.f};
    #pragma unroll
    for (int ks = 0; ks < 4; ++ks) {
        bf16x8 af[2], bfr[8];
        #pragma unroll
        for (int rt = 0; rt < 2; ++rt) {
            int r = wv * 32 + rt * 16 + (lane & 15);
            int byte = r * 256 + ((ks * 64 + (lane >> 4) * 16) ^ ((r & 7) << 4));
            af[rt] = *(const bf16x8*)((const char*)Al + byte);
        }
        #pragma unroll
        for (int ct = 0; ct < 8; ++ct) {
            int r = ct * 16 + (lane & 15);
            int byte = r * 256 + ((ks * 64 + (lane >> 4) * 16) ^ ((r & 7) << 4));
            bfr[ct] = *(const bf16x8*)((const char*)Wl + byte);
        }
        #pragma unroll
        for (int rt = 0; rt < 2; ++rt)
            #pragma unroll
            for (int ct = 0; ct < 8; ++ct)
                acc[rt][ct] = __builtin_amdgcn_mfma_f32_16x16x32_bf16(
                    af[rt], bfr[ct], acc[rt][ct], 0, 0, 0);
    }
    #pragma unroll
    for (int rt = 0; rt < 2; ++rt) {
        #pragma unroll
        for (int ct = 0; ct < 8; ++ct) {
            int gcol = col0 + ct * 16 + (lane & 15);
            float bv = bias[gcol];
            #pragma unroll
            for (int r = 0; r < 4; ++r) {
                int grow = row0 + wv * 32 + rt * 16 + (lane >> 4) * 4 + r;
                if (grow >= nrows) continue;
                Y[(size_t)grow * 512 + gcol] = f2bf(acc[rt][ct][r] + bv);
            }
        }
    }
}

// ---------------- Fused FFN, K-split: out = xnew + gelu(h2@W1+b1)@W2 + b2 ----------
// 4 quarters of 64 hidden channels; each quarter: GEMM1 -> gelu -> Hl (16KB) ->
// GEMM2 partial accumulate. LDS 80 KB (Xl 32 + W1l 16 + Hl 16 + W2l 16) -> 2 blocks/CU.
__global__ __launch_bounds__(256) void ffn_fused(
    const ushort* __restrict__ A, const ushort* __restrict__ W1T,
    const ushort* __restrict__ W2T, const float* __restrict__ b1,
    const float* __restrict__ b2, const float* __restrict__ xnew,
    float* __restrict__ out, int nrows)
{
    __shared__ __align__(16) ushort Xl[128 * 128];   // 32 KB
    __shared__ __align__(16) ushort W1l[64 * 128];   // 16 KB
    __shared__ __align__(16) ushort Hl[128 * 64];    // 16 KB
    __shared__ __align__(16) ushort W2l[128 * 64];   // 16 KB
    int tid = threadIdx.x;
    int wv = tid >> 6, lane = tid & 63;
    int row0 = blockIdx.x * 128;

    // stage Xl (h2 rows, swizzled)
    #pragma unroll
    for (int i = 0; i < 8; ++i) {
        int c = tid + i * 256;
        int r = c >> 4, c16 = c & 15;
        int gr = row0 + r;
        ulonglong2 val = {0ull, 0ull};
        if (gr < nrows) val = *(const ulonglong2*)(A + (size_t)gr * 128 + c16 * 8);
        int byte = r * 256 + ((c16 * 16) ^ ((r & 7) << 4));
        *(ulonglong2*)((char*)Xl + byte) = val;
    }

    f32x4 acc2[2][8];   // persistent: 128 out cols
    #pragma unroll
    for (int i = 0; i < 2; ++i)
        #pragma unroll
        for (int j = 0; j < 8; ++j) acc2[i][j] = (f32x4){0.f, 0.f, 0.f, 0.f};

    for (int q = 0; q < 4; ++q) {
        // stage W1l = W1T rows [q*64, q*64+64) : [64][128k], 1024 chunks
        #pragma unroll
        for (int i = 0; i < 4; ++i) {
            int c = tid + i * 256;
            int r = c >> 4, cc = c & 15;
            ulonglong2 val = *(const ulonglong2*)(W1T + (size_t)(q * 64 + r) * 128 + cc * 8);
            int byte = r * 256 + ((cc * 16) ^ ((r & 7) << 4));
            *(ulonglong2*)((char*)W1l + byte) = val;
        }
        // stage W2l = w2T[:, q*64 .. q*64+64) : [128 out][64 k], 1024 chunks
        #pragma unroll
        for (int i = 0; i < 4; ++i) {
            int c = tid + i * 256;
            int r = c >> 3, c8 = c & 7;
            ulonglong2 val = *(const ulonglong2*)(W2T + (size_t)r * 256 + q * 64 + c8 * 8);
            int byte = r * 128 + ((c8 * 16) ^ ((r & 7) << 4));
            *(ulonglong2*)((char*)W2l + byte) = val;
        }
        __syncthreads();

        // GEMM1 quarter: hidden[:, q*64..+64) = Xl @ W1q (K=128)
        f32x4 acc1[2][4];
        #pragma unroll
        for (int i = 0; i < 2; ++i)
            #pragma unroll
            for (int j = 0; j < 4; ++j) acc1[i][j] = (f32x4){0.f, 0.f, 0.f, 0.f};
        #pragma unroll
        for (int ks = 0; ks < 4; ++ks) {
            bf16x8 af[2], bfr[4];
            #pragma unroll
            for (int rt = 0; rt < 2; ++rt) {
                int r = wv * 32 + rt * 16 + (lane & 15);
                int byte = r * 256 + ((ks * 64 + (lane >> 4) * 16) ^ ((r & 7) << 4));
                af[rt] = *(const bf16x8*)((const char*)Xl + byte);
            }
            #pragma unroll
            for (int ct = 0; ct < 4; ++ct) {
                int r = ct * 16 + (lane & 15);
                int byte = r * 256 + ((ks * 64 + (lane >> 4) * 16) ^ ((r & 7) << 4));
                bfr[ct] = *(const bf16x8*)((const char*)W1l + byte);
            }
            #pragma unroll
            for (int rt = 0; rt < 2; ++rt)
                #pragma unroll
                for (int ct = 0; ct < 4; ++ct)
                    acc1[rt][ct] = __builtin_amdgcn_mfma_f32_16x16x32_bf16(
                        af[rt], bfr[ct], acc1[rt][ct], 0, 0, 0);
        }
        // bias + gelu -> Hl (row stride 128B, swizzled 16B chunks)
        #pragma unroll
        for (int rt = 0; rt < 2; ++rt) {
            #pragma unroll
            for (int ct = 0; ct < 4; ++ct) {
                int cl = ct * 16 + (lane & 15);          // local hidden col 0..63
                float bv = b1[q * 64 + cl];
                #pragma unroll
                for (int r = 0; r < 4; ++r) {
                    int row = wv * 32 + rt * 16 + (lane >> 4) * 4 + r;
                    float v = gelu_f(acc1[rt][ct][r] + bv);
                    int cb = cl * 2;
                    int byte = row * 128 + ((cb & ~15) ^ ((row & 7) << 4)) + (cb & 15);
                    *(ushort*)((char*)Hl + byte) = f2bf(v);
                }
            }
        }
        __syncthreads();

        // GEMM2 partial: acc2 += Hl @ W2q (K=64)
        #pragma unroll
        for (int ks = 0; ks < 2; ++ks) {
            bf16x8 af[2], bfr[8];
            #pragma unroll
            for (int rt = 0; rt < 2; ++rt) {
                int row = wv * 32 + rt * 16 + (lane & 15);
                int byte = row * 128 + ((ks * 64 + (lane >> 4) * 16) ^ ((row & 7) << 4));
                af[rt] = *(const bf16x8*)((const char*)Hl + byte);
            }
            #pragma unroll
            for (int ct = 0; ct < 8; ++ct) {
                int r = ct * 16 + (lane & 15);
                int byte = r * 128 + ((ks * 64 + (lane >> 4) * 16) ^ ((r & 7) << 4));
                bfr[ct] = *(const bf16x8*)((const char*)W2l + byte);
            }
            #pragma unroll
            for (int rt = 0; rt < 2; ++rt)
                #pragma unroll
                for (int ct = 0; ct < 8; ++ct)
                    acc2[rt][ct] = __builtin_amdgcn_mfma_f32_16x16x32_bf16(
                        af[rt], bfr[ct], acc2[rt][ct], 0, 0, 0);
        }
        __syncthreads();   // Hl/W tiles consumed before next-quarter restage
    }

    // epilogue: + b2 + xnew residual -> out (f32)
    #pragma unroll
    for (int rt = 0; rt < 2; ++rt) {
        #pragma unroll
        for (int ct = 0; ct < 8; ++ct) {
            int gcol = ct * 16 + (lane & 15);
            float bv = b2[gcol];
            #pragma unroll
            for (int r = 0; r < 4; ++r) {
                int grow = row0 + wv * 32 + rt * 16 + (lane >> 4) * 4 + r;
                if (grow >= nrows) continue;
                size_t idx = (size_t)grow * 128 + gcol;
                out[idx] = acc2[rt][ct][r] + bv + xnew[idx];
            }
        }
    }
}

// ---------------- Counting sort of edges by destination ----------------
__global__ void hist_kernel(const int* __restrict__ dst, int* __restrict__ deg)
{
    int e = blockIdx.x * 256 + threadIdx.x;
    if (e < N_EDGES) atomicAdd(&deg[dst[e]], 1);
}

__global__ void scan1_kernel(const int* __restrict__ deg, int* __restrict__ off,
                             int* __restrict__ bsum)
{
    __shared__ int sm[256];
    int i = blockIdx.x * 256 + threadIdx.x;
    int v = (i < N_NODES) ? deg[i] : 0;
    sm[threadIdx.x] = v;
    __syncthreads();
    #pragma unroll
    for (int d = 1; d < 256; d <<= 1) {
        int t = (threadIdx.x >= d) ? sm[threadIdx.x - d] : 0;
        __syncthreads();
        sm[threadIdx.x] += t;
        __syncthreads();
    }
    if (i < N_NODES) off[i] = sm[threadIdx.x] - v;
    if (threadIdx.x == 255) bsum[blockIdx.x] = sm[255];
}

__global__ void scan2_kernel(int* __restrict__ bsum, int nb)
{
    __shared__ int sm[256];
    int v = (threadIdx.x < nb) ? bsum[threadIdx.x] : 0;
    sm[threadIdx.x] = v;
    __syncthreads();
    #pragma unroll
    for (int d = 1; d < 256; d <<= 1) {
        int t = (threadIdx.x >= d) ? sm[threadIdx.x - d] : 0;
        __syncthreads();
        sm[threadIdx.x] += t;
        __syncthreads();
    }
    if (threadIdx.x < nb) bsum[threadIdx.x] = sm[threadIdx.x] - v;
}

__global__ void scan3_kernel(int* __restrict__ off, const int* __restrict__ bsum,
                             int* __restrict__ cursor)
{
    int i = blockIdx.x * 256 + threadIdx.x;
    if (i < N_NODES) {
        int o = off[i] + bsum[blockIdx.x];
        off[i] = o;
        cursor[i] = o;
    }
}

// scatter: src id + bf16 edge_attr row in destination-sorted order
// (random writes here buy SEQUENTIAL hot-loop reads in node_attn — r6 lesson)
__global__ void scatter_kernel(const int* __restrict__ dst, const int* __restrict__ src,
                               const float* __restrict__ eattr, int* __restrict__ cursor,
                               int* __restrict__ src_s, ushort* __restrict__ eattr_s)
{
    int e = blockIdx.x * 256 + threadIdx.x;
    if (e < N_EDGES) {
        int p = atomicAdd(&cursor[dst[e]], 1);
        src_s[p] = src[e];
        const float4* s4 = (const float4*)(eattr + (size_t)e * E_DIM);
        float4 f0 = s4[0], f1 = s4[1], f2 = s4[2], f3 = s4[3];
        uint4 u0, u1;
        u0.x = pack2(f0.x, f0.y); u0.y = pack2(f0.z, f0.w);
        u0.z = pack2(f1.x, f1.y); u0.w = pack2(f1.z, f1.w);
        u1.x = pack2(f2.x, f2.y); u1.y = pack2(f2.z, f2.w);
        u1.z = pack2(f3.x, f3.y); u1.w = pack2(f3.z, f3.w);
        uint4* d4 = (uint4*)(eattr_s + (size_t)p * E_DIM);
        d4[0] = u0; d4[1] = u1;
    }
}

// ---------------- Fused node attention (r9 EXACT) + beta + residual + LN2 ----------
// Lane l owns head h = l>>3, channels 2l, 2l+1 (j = l&7 -> ea comps 2j, 2j+1).
// 2-way unroll with DUAL accumulator state (r8/r10 lessons: do not restructure).
#define ATTN_STEP(P, S, A0, A1, E0, E1) do {                                         \
    int sv_ = src_s[P];                                                              \
    uint eap_ = *(const uint*)(eattr_s + (size_t)(P) * E_DIM + j2);                  \
    float ea0_ = bf2f((ushort)eap_), ea1_ = bf2f((ushort)(eap_ >> 16));              \
    size_t sb_ = (size_t)sv_ * 512;                                                  \
    uint kp_ = *(const uint*)(qkvs + sb_ + 128 + 2 * lane);                          \
    uint vp_ = *(const uint*)(qkvs + sb_ + 256 + 2 * lane);                          \
    float p_ = q0 * bf2f((ushort)kp_) + q1 * bf2f((ushort)(kp_ >> 16))               \
             + ea0_ * qp0 + ea1_ * qp1;                                              \
    p_ += __shfl_xor(p_, 1, 64);                                                     \
    p_ += __shfl_xor(p_, 2, 64);                                                     \
    p_ += __shfl_xor(p_, 4, 64);                                                     \
    float w_ = __expf(fminf(p_, 60.f));                                              \
    S  += w_;                                                                        \
    A0 += w_ * bf2f((ushort)vp_);                                                    \
    A1 += w_ * bf2f((ushort)(vp_ >> 16));                                            \
    E0 += w_ * ea0_;                                                                 \
    E1 += w_ * ea1_;                                                                 \
} while (0)

__global__ void node_attn(const ushort* __restrict__ qkvs, const float* __restrict__ x,
                          const float* __restrict__ we, const float* __restrict__ wbeta,
                          const float* __restrict__ ln2g, const float* __restrict__ ln2b,
                          const int* __restrict__ off, const int* __restrict__ deg,
                          const int* __restrict__ src_s, const ushort* __restrict__ eattr_s,
                          float* __restrict__ xnew, ushort* __restrict__ h2)
{
    __shared__ float wl[E_DIM * 128];     // we row-major [16][128], 8 KB
    __shared__ float weT[128 * 17];       // we transposed [128][16+pad], 8.5 KB
    __shared__ float sc4[4][128];         // per-wave scratch, 2 KB
    for (int t = threadIdx.x; t < E_DIM * 32; t += 256)
        *(float4*)&wl[t * 4] = *(const float4*)&we[t * 4];
    for (int t = threadIdx.x; t < E_DIM * 128; t += 256) {
        int j = t >> 7, ch = t & 127;
        weT[ch * 17 + j] = we[t];
    }
    __syncthreads();

    int nl   = threadIdx.x >> 6;
    int node = blockIdx.x * 4 + nl;
    int lane = threadIdx.x & 63;
    if (node >= N_NODES) return;

    int j2 = (lane & 7) * 2;              // this lane's ea component pair
    int hb = (lane >> 3) * 16;            // head channel base

    size_t nb = (size_t)node * 512;
    uint qp = *(const uint*)(qkvs + nb + 2 * lane);
    float q0r = bf2f((ushort)qp), q1r = bf2f((ushort)(qp >> 16));

    sc4[nl][2 * lane]     = q0r;
    sc4[nl][2 * lane + 1] = q1r;
    float qp0 = 0.f, qp1 = 0.f;
    #pragma unroll
    for (int c = 0; c < 16; ++c) {
        float qc = sc4[nl][hb + c];
        qp0 += qc * weT[(hb + c) * 17 + j2];
        qp1 += qc * weT[(hb + c) * 17 + j2 + 1];
    }
    float q0 = q0r * 0.25f, q1 = q1r * 0.25f;   // fold 1/sqrt(C)
    qp0 *= 0.25f; qp1 *= 0.25f;

    float SA = 0.f, A0a = 0.f, A1a = 0.f, E0a = 0.f, E1a = 0.f;
    float SB = 0.f, A0b = 0.f, A1b = 0.f, E0b = 0.f, E1b = 0.f;

    int o = off[node], dg = deg[node];
    int i = 0;
    for (; i + 2 <= dg; i += 2) {
        ATTN_STEP(o + i,     SA, A0a, A1a, E0a, E1a);
        ATTN_STEP(o + i + 1, SB, A0b, A1b, E0b, E1b);
    }
    if (i < dg)
        ATTN_STEP(o + i, SA, A0a, A1a, E0a, E1a);

    float S  = SA + SB;
    float A0 = A0a + A0b, A1 = A1a + A1b;
    float E0 = E0a + E0b, E1 = E1a + E1b;

    sc4[nl][2 * lane]     = E0;
    sc4[nl][2 * lane + 1] = E1;
    float ep0 = 0.f, ep1 = 0.f;
    #pragma unroll
    for (int j = 0; j < 16; ++j) {
        float es = sc4[nl][hb + j];
        ep0 += es * wl[j * 128 + 2 * lane];
        ep1 += es * wl[j * 128 + 2 * lane + 1];
    }

    float rinv = 1.f / (S + 1e-16f);
    float o0 = (A0 + ep0) * rinv;
    float o1 = (A1 + ep1) * rinv;

    uint xrp = *(const uint*)(qkvs + nb + 384 + 2 * lane);
    float xr0 = bf2f((ushort)xrp), xr1 = bf2f((ushort)(xrp >> 16));
    float2 wb0 = *(const float2*)&wbeta[2 * lane];
    float2 wb1 = *(const float2*)&wbeta[128 + 2 * lane];
    float2 wb2 = *(const float2*)&wbeta[256 + 2 * lane];
    float dot = o0 * wb0.x + o1 * wb0.y + xr0 * wb1.x + xr1 * wb1.y
              + (o0 - xr0) * wb2.x + (o1 - xr1) * wb2.y;
    #pragma unroll
    for (int w = 32; w > 0; w >>= 1) dot += __shfl_xor(dot, w, 64);
    float beta = 1.f / (1.f + __expf(-dot));

    size_t xb = (size_t)node * D_MODEL + 2 * lane;
    float2 xv = *(const float2*)&x[xb];
    float ox = xv.x + beta * xr0 + (1.f - beta) * o0;
    float oy = xv.y + beta * xr1 + (1.f - beta) * o1;
    *(float2*)&xnew[xb] = make_float2(ox, oy);

    // ---- fused LN2 ----
    float s2  = ox + oy;
    float ss2 = ox * ox + oy * oy;
    #pragma unroll
    for (int w = 32; w > 0; w >>= 1) {
        s2  += __shfl_xor(s2,  w, 64);
        ss2 += __shfl_xor(ss2, w, 64);
    }
    float mu  = s2 * (1.0f / 128.0f);
    float var = ss2 * (1.0f / 128.0f) - mu * mu;
    float rs  = rsqrtf(var + 1e-5f);
    float2 g2 = *(const float2*)&ln2g[2 * lane];
    float2 b2 = *(const float2*)&ln2b[2 * lane];
    float h0 = (ox - mu) * rs * g2.x + b2.x;
    float h1 = (oy - mu) * rs * g2.y + b2.y;
    ((uint*)h2)[(size_t)node * 64 + lane] = pack2(h0, h1);
}

extern "C" void kernel_launch(void* const* d_in, const int* in_sizes, int n_in,
                              void* d_out, int out_size, void* d_ws, size_t ws_size,
                              hipStream_t stream)
{
    const float* x     = (const float*)d_in[0];
    const int*   eidx  = (const int*)  d_in[1];
    const float* eattr = (const float*)d_in[2];
    const float* wq  = (const float*)d_in[3];  const float* bq  = (const float*)d_in[4];
    const float* wk  = (const float*)d_in[5];  const float* bk  = (const float*)d_in[6];
    const float* wv  = (const float*)d_in[7];  const float* bv  = (const float*)d_in[8];
    const float* we  = (const float*)d_in[9];
    const float* wsk = (const float*)d_in[10]; const float* bsk = (const float*)d_in[11];
    const float* wbeta = (const float*)d_in[12];
    const float* ln1g = (const float*)d_in[13]; const float* ln1b = (const float*)d_in[14];
    const float* ln2g = (const float*)d_in[15]; const float* ln2b = (const float*)d_in[16];
    const float* w1 = (const float*)d_in[17]; const float* b1 = (const float*)d_in[18];
    const float* w2 = (const float*)d_in[19]; const float* b2 = (const float*)d_in[20];
    const int* srcp = eidx;
    const int* dstp = eidx + N_EDGES;
    float* out = (float*)d_out;

    char* w = (char*)d_ws;
    size_t o = 0;
    ushort* qkvs_b  = (ushort*)(w + o);  o += (size_t)N_NODES * 512 * 2;   // 51.2MB
    float* xnew = (float*)(w + o);  o += (size_t)N_NODES * 128 * 4;        // 25.6MB
    ushort* eattr_s = (ushort*)(w + o); o += (size_t)N_EDGES * E_DIM * 2;  // 25.6MB
    int* src_s = (int*)(w + o);     o += (size_t)N_EDGES * 4;              // 3.2MB
    ushort* h2_b = (ushort*)(w + o); o += (size_t)N_NODES * 128 * 2;       // 12.8MB
    ushort* wqkvsT = (ushort*)(w + o); o += 512 * 128 * 2;
    ushort* w1T    = (ushort*)(w + o); o += 256 * 128 * 2;
    ushort* w2T    = (ushort*)(w + o); o += 128 * 256 * 2;
    float*  bqkvs  = (float*)(w + o);  o += 4096;
    int* deg    = (int*)(w + o); o += 200704;
    int* offb   = (int*)(w + o); o += 200704;
    int* cursor = (int*)(w + o); o += 200704;
    int* bsum   = (int*)(w + o); o += 4096;

    dim3 blk(256);
    dim3 lngrid((N_NODES + 3) / 4);
    const int NB = (N_NODES + 255) / 256;
    const int EB = (N_EDGES + 255) / 256;
    const int GB = (N_NODES + 127) / 128;

    prep_weights<<<dim3(256), blk, 0, stream>>>(wq, wk, wv, wsk, bq, bk, bv, bsk,
                                                w1, w2, wqkvsT, bqkvs, w1T, w2T, deg);
    // fused LN1 + projections -> qkvs bf16 [N][512] (BN=128: 4 col-tiles)
    proj_ln_gemm<<<dim3(GB, 4), blk, 0, stream>>>(x, ln1g, ln1b, wqkvsT, bqkvs,
                                                  qkvs_b, N_NODES);
    hist_kernel<<<dim3(EB), blk, 0, stream>>>(dstp, deg);
    scan1_kernel<<<dim3(NB), blk, 0, stream>>>(deg, offb, bsum);
    scan2_kernel<<<dim3(1), blk, 0, stream>>>(bsum, NB);
    scan3_kernel<<<dim3(NB), blk, 0, stream>>>(offb, bsum, cursor);
    scatter_kernel<<<dim3(EB), blk, 0, stream>>>(dstp, srcp, eattr, cursor, src_s, eattr_s);
    node_attn<<<lngrid, blk, 0, stream>>>(qkvs_b, x, we, wbeta, ln2g, ln2b,
                                          offb, deg, src_s, eattr_s, xnew, h2_b);
    // fused FFN (K-split) + residual -> d_out
    ffn_fused<<<dim3(GB), blk, 0, stream>>>(h2_b, w1T, w2T, b1, b2, xnew, out, N_NODES);
}